// Round 17
// baseline (277.407 us; speedup 1.0000x reference)
//
#include <hip/hip_runtime.h>
#include <hip/hip_bf16.h>

// B=4, T=1024, E=512, H=8. Two-pass attention:
//   cast5 -> {QK proj + Vt} one dispatch (gemm_bt3, m97-regime) -> S=QK^T*a
//   (gemm_bt2) -> softmax -> O=P.V (gemm_bt2) -> out split-K=8 (gemm_bt2)
//   -> reduce(+bias).
// gemm_bt2 (R12-proven): 256x256, BK=32, 512thr/8w, 3-buf counted-vmcnt.
// gemm_bt3 (NEW, m97 occupancy regime): 128x128, BK=32, 256thr/4w, 3-buf
// counted-vmcnt, 48KB LDS -> 3 blocks/CU (12 waves/CU): cross-block overlap
// absorbs per-step barrier bubbles (m97: 874-912 TF with this shape/occ).
// MEASURED LAWS (R5-R16): 512-thr (512,1) no spill; higher arg spills acc.
// 256-thr (256,3): cap 512/3=170 -> no spill at ~115 need. Fragment-major
// LDS = conflict-free ds_read_b128 (SQ_LDS_BANK_CONFLICT=0 all rounds).
// T1 bijective XCD swizzle (all grids % 8 == 0). gemm_bt2 pins at 546-600 TF
// (m233 2-phase ceiling) across BK/buffers/phases/occ -- R17 tests the m97
// occupancy escape on the largest dispatch only.
// Layouts: Q,K [b,t,h,e] ld 4096; Vt [h*e, b*t]; S/P [b,h,q,k]; O [b,t,h*e].

typedef short bf16x8 __attribute__((ext_vector_type(8)));
typedef float f32x4 __attribute__((ext_vector_type(4)));
typedef unsigned short u16x8 __attribute__((ext_vector_type(8)));

__device__ __forceinline__ unsigned short f2bf(float f) {
  unsigned int u = __float_as_uint(f);
  u += 0x7FFFu + ((u >> 16) & 1u);            // RNE, finite inputs
  return (unsigned short)(u >> 16);
}
__device__ __forceinline__ float bf2f(unsigned short s) {
  return __uint_as_float(((unsigned int)s) << 16);
}

typedef const __attribute__((address_space(1))) unsigned int* gas1_t;
typedef __attribute__((address_space(3))) unsigned int* las3_t;

__device__ __forceinline__ void gload16(const unsigned short* g, unsigned short* l) {
  __builtin_amdgcn_global_load_lds((gas1_t)g, (las3_t)l, 16, 0, 0);
}

__device__ __forceinline__ void store_val(unsigned short* p, float v) { *p = f2bf(v); }
__device__ __forceinline__ void store_val(float* p, float v) { *p = v; }

// ---------------- 256x256-tile BT GEMM, BK=32, 3-buf counted-vmcnt ----------------
template<typename OutT>
__global__ __launch_bounds__(512, 1) void gemm_bt2(
    const unsigned short* __restrict__ A, const unsigned short* __restrict__ B,
    OutT* __restrict__ C,
    int K, int lda, int ldb, int ldc, int zshift,
    long long sAb, long long sAh, long long sBb, long long sBh,
    long long sCb, long long sCh, float alpha)
{
  const int tid  = threadIdx.x;
  const int lane = tid & 63;
  const int wave = tid >> 6;
  const int l15 = lane & 15, lhi = lane >> 4;
  const int wm = wave >> 2, wn = wave & 3;           // 2M x 4N wave grid

  const int nx = gridDim.x, nxy = gridDim.x * gridDim.y;
  const int nwg = nxy * gridDim.z;
  int flat = blockIdx.x + nx * blockIdx.y + nxy * blockIdx.z;
  flat = (flat & 7) * (nwg >> 3) + (flat >> 3);
  const int bz = flat / nxy;
  const int rem = flat - bz * nxy;
  const int by = rem / nx;
  const int bx = rem - by * nx;

  const int bb = bz >> zshift, hh = bz & ((1 << zshift) - 1);
  const long long m0 = (long long)by * 256;
  const long long n0 = (long long)bx * 256;

  const unsigned short* Ab = A + bb * sAb + hh * sAh;
  const unsigned short* Bb = B + bb * sBb + hh * sBh;

  __shared__ __align__(16) unsigned short lds[49152];  // 96 KB, 3 buffers

  const unsigned short* gA[2];
  const unsigned short* gB[2];
  int fidx[2];
#pragma unroll
  for (int c = 0; c < 2; ++c) {
    const int f = c * 8 + wave;
    fidx[c] = f;
    gA[c] = Ab + (size_t)(m0 + f * 16 + l15) * lda + lhi * 8;
    gB[c] = Bb + (size_t)(n0 + f * 16 + l15) * ldb + lhi * 8;
  }

  auto stage = [&](int n, int p) {
    unsigned short* dst = lds + p * 16384;
    const int ko = n * 32;
#pragma unroll
    for (int c = 0; c < 2; ++c) {
      gload16(gA[c] + ko, dst + fidx[c] * 512);
      gload16(gB[c] + ko, dst + 8192 + fidx[c] * 512);
    }
  };

  f32x4 acc[8][4];
#pragma unroll
  for (int m = 0; m < 8; ++m)
#pragma unroll
    for (int n = 0; n < 4; ++n) acc[m][n] = (f32x4){0.f, 0.f, 0.f, 0.f};

  const int nt = K >> 5;
  stage(0, 0);
  stage(1, 1);
  asm volatile("s_waitcnt vmcnt(4)" ::: "memory");
  __builtin_amdgcn_sched_barrier(0);
  __builtin_amdgcn_s_barrier();

  for (int t = 0; t < nt; ++t) {
    const bool pref = (t + 2 < nt);
    if (pref) stage(t + 2, (t + 2) % 3);
    const unsigned short* base = lds + (t % 3) * 16384;
    bf16x8 af[8], bf[4];
#pragma unroll
    for (int mf = 0; mf < 8; ++mf)
      af[mf] = *(const bf16x8*)(base + (wm * 8 + mf) * 512 + lane * 8);
#pragma unroll
    for (int nf = 0; nf < 4; ++nf)
      bf[nf] = *(const bf16x8*)(base + 8192 + (wn * 4 + nf) * 512 + lane * 8);
    __builtin_amdgcn_s_setprio(1);
#pragma unroll
    for (int mf = 0; mf < 8; ++mf)
#pragma unroll
      for (int nf = 0; nf < 4; ++nf)
        acc[mf][nf] = __builtin_amdgcn_mfma_f32_16x16x32_bf16(af[mf], bf[nf], acc[mf][nf], 0, 0, 0);
    __builtin_amdgcn_s_setprio(0);
    if (pref) asm volatile("s_waitcnt vmcnt(4)" ::: "memory");
    else      asm volatile("s_waitcnt vmcnt(0)" ::: "memory");
    __builtin_amdgcn_sched_barrier(0);
    __builtin_amdgcn_s_barrier();
    __builtin_amdgcn_sched_barrier(0);
  }

  OutT* Cb = C + bb * sCb + hh * sCh;
#pragma unroll
  for (int mf = 0; mf < 8; ++mf) {
#pragma unroll
    for (int nf = 0; nf < 4; ++nf) {
      const long long col = n0 + wn * 64 + nf * 16 + l15;
#pragma unroll
      for (int r = 0; r < 4; ++r) {
        const long long row = m0 + wm * 128 + mf * 16 + lhi * 4 + r;
        store_val(Cb + (size_t)row * ldc + col, acc[mf][nf][r] * alpha);
      }
    }
  }
}

// ---------------- 128x128-tile BT GEMM, BK=32, 3-buf, m97 occupancy regime ----------------
// 256 thr / 4 waves (2M x 2N), per-wave 64x64 out (acc 64 AGPR). LDS buffer p
// at elems [p*8192,+8192): A frags 0..7 [0,4096), B frags [4096,8192).
// Wave w stages A frags {2w,2w+1} + B frags {2w,2w+1} = 4 gload16/step.
// vtSel: batch hh==vtSel swaps pointers (merges Vt GEMM into proj dispatch).
template<typename OutT>
__global__ __launch_bounds__(256, 3) void gemm_bt3(
    const unsigned short* __restrict__ A, const unsigned short* __restrict__ B,
    OutT* __restrict__ C,
    const unsigned short* __restrict__ A2, const unsigned short* __restrict__ B2,
    OutT* __restrict__ C2, int vtSel,
    int K, int lda, int ldb, int ldc, int zshift,
    long long sAb, long long sAh, long long sBb, long long sBh,
    long long sCb, long long sCh, float alpha)
{
  const int tid  = threadIdx.x;
  const int lane = tid & 63;
  const int wave = tid >> 6;
  const int l15 = lane & 15, lhi = lane >> 4;
  const int wm = wave >> 1, wn = wave & 1;           // 2M x 2N wave grid

  // T1: bijective XCD chunk swizzle (nwg % 8 == 0)
  const int nx = gridDim.x, nxy = gridDim.x * gridDim.y;
  const int nwg = nxy * gridDim.z;
  int flat = blockIdx.x + nx * blockIdx.y + nxy * blockIdx.z;
  flat = (flat & 7) * (nwg >> 3) + (flat >> 3);
  const int bz = flat / nxy;
  const int rem = flat - bz * nxy;
  const int by = rem / nx;
  const int bx = rem - by * nx;

  const int bb = bz >> zshift, hh = bz & ((1 << zshift) - 1);
  const long long m0 = (long long)by * 128;
  const long long n0 = (long long)bx * 128;

  const unsigned short* Ab;
  const unsigned short* Bb;
  OutT* Cb;
  if (hh == vtSel) { Ab = A2; Bb = B2; Cb = C2; }
  else {
    Ab = A + bb * sAb + hh * sAh;
    Bb = B + bb * sBb + hh * sBh;
    Cb = C + bb * sCb + hh * sCh;
  }

  __shared__ __align__(16) unsigned short lds[24576];  // 48 KB, 3 buffers

  const unsigned short* gA[2];
  const unsigned short* gB[2];
  int fidx[2];
#pragma unroll
  for (int c = 0; c < 2; ++c) {
    const int f = wave * 2 + c;                      // frags 0..7
    fidx[c] = f;
    gA[c] = Ab + (size_t)(m0 + f * 16 + l15) * lda + lhi * 8;
    gB[c] = Bb + (size_t)(n0 + f * 16 + l15) * ldb + lhi * 8;
  }

  auto stage = [&](int n, int p) {
    unsigned short* dst = lds + p * 8192;
    const int ko = n * 32;
#pragma unroll
    for (int c = 0; c < 2; ++c) {
      gload16(gA[c] + ko, dst + fidx[c] * 512);
      gload16(gB[c] + ko, dst + 4096 + fidx[c] * 512);
    }
  };

  f32x4 acc[4][4];
#pragma unroll
  for (int m = 0; m < 4; ++m)
#pragma unroll
    for (int n = 0; n < 4; ++n) acc[m][n] = (f32x4){0.f, 0.f, 0.f, 0.f};

  const int nt = K >> 5;
  stage(0, 0);
  stage(1, 1);
  asm volatile("s_waitcnt vmcnt(4)" ::: "memory");   // tile 0's 4 loads landed
  __builtin_amdgcn_sched_barrier(0);
  __builtin_amdgcn_s_barrier();

  for (int t = 0; t < nt; ++t) {
    const bool pref = (t + 2 < nt);
    if (pref) stage(t + 2, (t + 2) % 3);             // in flight past barrier
    const unsigned short* base = lds + (t % 3) * 8192;
    bf16x8 af[4], bf[4];
#pragma unroll
    for (int mf = 0; mf < 4; ++mf)
      af[mf] = *(const bf16x8*)(base + (wm * 4 + mf) * 512 + lane * 8);
#pragma unroll
    for (int nf = 0; nf < 4; ++nf)
      bf[nf] = *(const bf16x8*)(base + 4096 + (wn * 4 + nf) * 512 + lane * 8);
    __builtin_amdgcn_s_setprio(1);
#pragma unroll
    for (int mf = 0; mf < 4; ++mf)
#pragma unroll
      for (int nf = 0; nf < 4; ++nf)
        acc[mf][nf] = __builtin_amdgcn_mfma_f32_16x16x32_bf16(af[mf], bf[nf], acc[mf][nf], 0, 0, 0);
    __builtin_amdgcn_s_setprio(0);
    if (pref) asm volatile("s_waitcnt vmcnt(4)" ::: "memory");
    else      asm volatile("s_waitcnt vmcnt(0)" ::: "memory");
    __builtin_amdgcn_sched_barrier(0);
    __builtin_amdgcn_s_barrier();
    __builtin_amdgcn_sched_barrier(0);
  }

  // C/D layout (m89/m91): col = lane&15, row = (lane>>4)*4 + reg
#pragma unroll
  for (int mf = 0; mf < 4; ++mf) {
#pragma unroll
    for (int nf = 0; nf < 4; ++nf) {
      const long long col = n0 + wn * 64 + nf * 16 + l15;
#pragma unroll
      for (int r = 0; r < 4; ++r) {
        const long long row = m0 + wm * 64 + mf * 16 + lhi * 4 + r;
        store_val(Cb + (size_t)row * ldc + col, acc[mf][nf][r] * alpha);
      }
    }
  }
}

// ---------------- split-K reduce: out = sum(partials) + bias ----------------
__global__ __launch_bounds__(256) void reduce_kernel(
    const float* __restrict__ P, const float* __restrict__ bias,
    float* __restrict__ out)
{
  const int i = blockIdx.x * 256 + threadIdx.x;
  const int col4 = i & 127;
  const float4* p4 = (const float4*)P + i;
  float4 s = p4[0];
#pragma unroll
  for (int z = 1; z < 8; ++z) {
    float4 v = p4[(size_t)z * 524288];
    s.x += v.x; s.y += v.y; s.z += v.z; s.w += v.w;
  }
  float4 b = ((const float4*)bias)[col4];
  s.x += b.x; s.y += b.y; s.z += b.z; s.w += b.w;
  ((float4*)out)[i] = s;
}

// ---------------- fused fp32 -> bf16 cast of all 5 tensors ----------------
__global__ __launch_bounds__(256) void cast5_kernel(
    const float* __restrict__ s0, const float* __restrict__ s1,
    const float* __restrict__ s2, const float* __restrict__ s3,
    const float* __restrict__ s4, unsigned short* __restrict__ dst)
{
  const int seg = blockIdx.x >> 11;
  const int off = (blockIdx.x & 2047) * 256 + threadIdx.x;
  const float* s = s0;
  if (seg == 1) s = s1; else if (seg == 2) s = s2;
  else if (seg == 3) s = s3; else if (seg == 4) s = s4;
  float4 v = ((const float4*)s)[off];
  ushort4 o;
  o.x = f2bf(v.x); o.y = f2bf(v.y); o.z = f2bf(v.z); o.w = f2bf(v.w);
  ((ushort4*)dst)[(size_t)seg * 524288 + off] = o;
}

// ---------------- in-place row softmax over S (bf16), logit = S - mask ----------------
__global__ __launch_bounds__(256) void softmax_kernel(
    unsigned short* __restrict__ S, const float* __restrict__ mask)
{
  const int wave = threadIdx.x >> 6;
  const int lane = threadIdx.x & 63;
  const long long row = (long long)blockIdx.x * 4 + wave;   // 0..32767
  const int q = (int)(row & 1023);
  const int b = (int)(row >> 13);
  unsigned short* Srow = S + row * 1024;
  const float* mrow = mask + ((size_t)b * 1024 + q) * 1024;

  u16x8 sv0 = ((const u16x8*)Srow)[lane * 2];
  u16x8 sv1 = ((const u16x8*)Srow)[lane * 2 + 1];
  float mk[16];
  const float4* m4 = (const float4*)mrow + lane * 4;
#pragma unroll
  for (int t = 0; t < 4; ++t) {
    float4 v = m4[t];
    mk[t * 4 + 0] = v.x; mk[t * 4 + 1] = v.y; mk[t * 4 + 2] = v.z; mk[t * 4 + 3] = v.w;
  }

  float lg[16];
#pragma unroll
  for (int j = 0; j < 8; ++j) lg[j] = bf2f(sv0[j]) - mk[j];
#pragma unroll
  for (int j = 0; j < 8; ++j) lg[8 + j] = bf2f(sv1[j]) - mk[8 + j];

  float mx = lg[0];
#pragma unroll
  for (int j = 1; j < 16; ++j) mx = fmaxf(mx, lg[j]);
#pragma unroll
  for (int off = 32; off > 0; off >>= 1) mx = fmaxf(mx, __shfl_xor(mx, off));

  float ex[16], sm = 0.f;
#pragma unroll
  for (int j = 0; j < 16; ++j) { ex[j] = __expf(lg[j] - mx); sm += ex[j]; }
#pragma unroll
  for (int off = 32; off > 0; off >>= 1) sm += __shfl_xor(sm, off);
  const float rinv = 1.0f / sm;

  u16x8 o0, o1;
#pragma unroll
  for (int j = 0; j < 8; ++j) o0[j] = f2bf(ex[j] * rinv);
#pragma unroll
  for (int j = 0; j < 8; ++j) o1[j] = f2bf(ex[8 + j] * rinv);
  ((u16x8*)Srow)[lane * 2] = o0;
  ((u16x8*)Srow)[lane * 2 + 1] = o1;
}

extern "C" void kernel_launch(void* const* d_in, const int* in_sizes, int n_in,
                              void* d_out, int out_size, void* d_ws, size_t ws_size,
                              hipStream_t stream) {
  const float* x    = (const float*)d_in[0];
  const float* mask = (const float*)d_in[1];
  const float* Wk   = (const float*)d_in[2];
  const float* Wq   = (const float*)d_in[3];
  const float* Wv   = (const float*)d_in[4];
  const float* Wu   = (const float*)d_in[5];
  const float* bu   = (const float*)d_in[6];

  const size_t MB = 1024 * 1024;
  if (ws_size < 212 * MB) return;
  char* ws = (char*)d_ws;
  unsigned short* xb  = (unsigned short*)(ws + 0 * MB);    // 4MB  [4096,512]
  unsigned short* Wqb = (unsigned short*)(ws + 4 * MB);
  unsigned short* Wkb = (unsigned short*)(ws + 8 * MB);
  unsigned short* Wvb = (unsigned short*)(ws + 12 * MB);
  unsigned short* Wub = (unsigned short*)(ws + 16 * MB);
  unsigned short* Qb  = (unsigned short*)(ws + 20 * MB);   // 32MB [b,t,h,e]
  unsigned short* Kb  = (unsigned short*)(ws + 52 * MB);   // 32MB
  unsigned short* Vt  = (unsigned short*)(ws + 84 * MB);   // 32MB [h*e, b*t]
  unsigned short* Sb  = (unsigned short*)(ws + 116 * MB);  // 64MB [b,h,q,k]
  unsigned short* Ob  = (unsigned short*)(ws + 180 * MB);  // 32MB [b,t,h*e]
  float* Pk = (float*)(ws + 20 * MB);  // split-K partials overlay Qb/Kb (dead post-attn)

  cast5_kernel<<<5 * 2048, 256, 0, stream>>>(x, Wq, Wk, Wv, Wu, xb);

  // Q proj (hh=0), K proj (hh=1), Vt (hh=2) -- gemm_bt3, m97 occupancy regime
  // nwg = 32*32*3 = 3072 (%8==0), ~12 blocks/CU total rounds, 3 co-resident
  gemm_bt3<unsigned short><<<dim3(32, 32, 3), 256, 0, stream>>>(
      xb, Wqb, Qb, Wvb, xb, Vt, 2,
      512, 512, 512, 4096, 2,
      0, 0, 0, 2097152LL, 0, 16777216LL, 1.0f);

  // S = (1/sqrt(512)) * Q.K^T per (b,h)   (M=N=1024, K=512, 32 batches)
  gemm_bt2<unsigned short><<<dim3(4, 4, 32), 512, 0, stream>>>(
      Qb, Kb, Sb,
      512, 4096, 4096, 1024, 3,
      4194304LL, 512LL, 4194304LL, 512LL, 8388608LL, 1048576LL,
      0.044194173824159216f);

  // P = softmax(S - mask) in place
  softmax_kernel<<<8192, 256, 0, stream>>>(Sb, mask);

  // O = P.V   (M=1024, N=512, K=1024, 32 batches)
  gemm_bt2<unsigned short><<<dim3(2, 4, 32), 512, 0, stream>>>(
      Sb, Vt, Ob,
      1024, 1024, 4096, 4096, 3,
      8388608LL, 1048576LL, 1024LL, 2097152LL, 4194304LL, 512LL, 1.0f);

  // out partials: split-K=8 over K=4096 (M=4096, N=512, slice=512)
  gemm_bt2<float><<<dim3(2, 16, 8), 512, 0, stream>>>(
      Ob, Wub, Pk,
      512, 4096, 4096, 512, 0,
      512LL, 0, 512LL, 0, 2097152LL, 0, 1.0f);

  // out = sum_z Pk[z] + bu
  reduce_kernel<<<2048, 256, 0, stream>>>(Pk, bu, (float*)d_out);
}

// Round 18
// 242.370 us; speedup vs baseline: 1.1446x; 1.1446x over previous
//
#include <hip/hip_runtime.h>
#include <hip/hip_bf16.h>

// B=4, T=1024, E=512, H=8. Two-pass attention with ALGEBRAIC REWRITE:
//   S_h = Q_h.K_h^T = x.(Wq_h^T.Wk_h).x^T  -- so Q-proj and K-proj (2x17.2GF)
//   are replaced by N_h = Wk_h^T.Wq_h (2.1GF) + xM = x.M_h (17.2GF).
// Pipeline: cast5 -> wtrans (Wq,Wk head-transpose) -> Nh (batched 512^3)
//   -> xM (=x.M_h, Q-like layout) -> Vt (=Wv.x^T) -> S = xM.x^T * a
//   -> softmax(S-mask) -> O=P.V -> out split-K=8 -> reduce(+bias).
// gemm_bt2 (R12/R16-proven, UNCHANGED): 256x256, BK=32, 512thr/8w, 3-buf
// counted-vmcnt (stage t+2, vmcnt(4) keeps t+2 in flight), T5 setprio,
// T1 bijective XCD swizzle (all grids % 8 == 0).
// MEASURED LAWS (R5-R17): (512,1) no spill; higher arg spills acc. Fragment-
// major LDS = conflict-free (SQ_LDS_BANK_CONFLICT=0). GEMM rate pins at
// ~550-600 TF across BK/buffers/phases/occupancy/tile (2-phase structural
// ceiling, m233) -> this round cuts FLOPs instead of chasing rate.
// Layouts: xM [b,t,h,j] ld 4096 (Q-like); Vt [h*e, b*t]; S/P [b,h,q,k];
//          O [b,t,h*e]; Wqt/Wkt [h][i][k]; Nh [h][512][512].

typedef short bf16x8 __attribute__((ext_vector_type(8)));
typedef float f32x4 __attribute__((ext_vector_type(4)));
typedef unsigned short u16x8 __attribute__((ext_vector_type(8)));

__device__ __forceinline__ unsigned short f2bf(float f) {
  unsigned int u = __float_as_uint(f);
  u += 0x7FFFu + ((u >> 16) & 1u);            // RNE, finite inputs
  return (unsigned short)(u >> 16);
}
__device__ __forceinline__ float bf2f(unsigned short s) {
  return __uint_as_float(((unsigned int)s) << 16);
}

typedef const __attribute__((address_space(1))) unsigned int* gas1_t;
typedef __attribute__((address_space(3))) unsigned int* las3_t;

__device__ __forceinline__ void gload16(const unsigned short* g, unsigned short* l) {
  __builtin_amdgcn_global_load_lds((gas1_t)g, (las3_t)l, 16, 0, 0);
}

__device__ __forceinline__ void store_val(unsigned short* p, float v) { *p = f2bf(v); }
__device__ __forceinline__ void store_val(float* p, float v) { *p = v; }

// ---------------- 256x256-tile BT GEMM, BK=32, 3-buf counted-vmcnt ----------------
template<typename OutT>
__global__ __launch_bounds__(512, 1) void gemm_bt2(
    const unsigned short* __restrict__ A, const unsigned short* __restrict__ B,
    OutT* __restrict__ C,
    int K, int lda, int ldb, int ldc, int zshift,
    long long sAb, long long sAh, long long sBb, long long sBh,
    long long sCb, long long sCh, float alpha)
{
  const int tid  = threadIdx.x;
  const int lane = tid & 63;
  const int wave = tid >> 6;
  const int l15 = lane & 15, lhi = lane >> 4;
  const int wm = wave >> 2, wn = wave & 3;           // 2M x 4N wave grid

  const int nx = gridDim.x, nxy = gridDim.x * gridDim.y;
  const int nwg = nxy * gridDim.z;
  int flat = blockIdx.x + nx * blockIdx.y + nxy * blockIdx.z;
  flat = (flat & 7) * (nwg >> 3) + (flat >> 3);
  const int bz = flat / nxy;
  const int rem = flat - bz * nxy;
  const int by = rem / nx;
  const int bx = rem - by * nx;

  const int bb = bz >> zshift, hh = bz & ((1 << zshift) - 1);
  const long long m0 = (long long)by * 256;
  const long long n0 = (long long)bx * 256;

  const unsigned short* Ab = A + bb * sAb + hh * sAh;
  const unsigned short* Bb = B + bb * sBb + hh * sBh;

  __shared__ __align__(16) unsigned short lds[49152];  // 96 KB, 3 buffers

  const unsigned short* gA[2];
  const unsigned short* gB[2];
  int fidx[2];
#pragma unroll
  for (int c = 0; c < 2; ++c) {
    const int f = c * 8 + wave;
    fidx[c] = f;
    gA[c] = Ab + (size_t)(m0 + f * 16 + l15) * lda + lhi * 8;
    gB[c] = Bb + (size_t)(n0 + f * 16 + l15) * ldb + lhi * 8;
  }

  auto stage = [&](int n, int p) {
    unsigned short* dst = lds + p * 16384;
    const int ko = n * 32;
#pragma unroll
    for (int c = 0; c < 2; ++c) {
      gload16(gA[c] + ko, dst + fidx[c] * 512);
      gload16(gB[c] + ko, dst + 8192 + fidx[c] * 512);
    }
  };

  f32x4 acc[8][4];
#pragma unroll
  for (int m = 0; m < 8; ++m)
#pragma unroll
    for (int n = 0; n < 4; ++n) acc[m][n] = (f32x4){0.f, 0.f, 0.f, 0.f};

  const int nt = K >> 5;
  stage(0, 0);
  stage(1, 1);
  asm volatile("s_waitcnt vmcnt(4)" ::: "memory");
  __builtin_amdgcn_sched_barrier(0);
  __builtin_amdgcn_s_barrier();

  for (int t = 0; t < nt; ++t) {
    const bool pref = (t + 2 < nt);
    if (pref) stage(t + 2, (t + 2) % 3);
    const unsigned short* base = lds + (t % 3) * 16384;
    bf16x8 af[8], bf[4];
#pragma unroll
    for (int mf = 0; mf < 8; ++mf)
      af[mf] = *(const bf16x8*)(base + (wm * 8 + mf) * 512 + lane * 8);
#pragma unroll
    for (int nf = 0; nf < 4; ++nf)
      bf[nf] = *(const bf16x8*)(base + 8192 + (wn * 4 + nf) * 512 + lane * 8);
    __builtin_amdgcn_s_setprio(1);
#pragma unroll
    for (int mf = 0; mf < 8; ++mf)
#pragma unroll
      for (int nf = 0; nf < 4; ++nf)
        acc[mf][nf] = __builtin_amdgcn_mfma_f32_16x16x32_bf16(af[mf], bf[nf], acc[mf][nf], 0, 0, 0);
    __builtin_amdgcn_s_setprio(0);
    if (pref) asm volatile("s_waitcnt vmcnt(4)" ::: "memory");
    else      asm volatile("s_waitcnt vmcnt(0)" ::: "memory");
    __builtin_amdgcn_sched_barrier(0);
    __builtin_amdgcn_s_barrier();
    __builtin_amdgcn_sched_barrier(0);
  }

  OutT* Cb = C + bb * sCb + hh * sCh;
#pragma unroll
  for (int mf = 0; mf < 8; ++mf) {
#pragma unroll
    for (int nf = 0; nf < 4; ++nf) {
      const long long col = n0 + wn * 64 + nf * 16 + l15;
#pragma unroll
      for (int r = 0; r < 4; ++r) {
        const long long row = m0 + wm * 128 + mf * 16 + lhi * 4 + r;
        store_val(Cb + (size_t)row * ldc + col, acc[mf][nf][r] * alpha);
      }
    }
  }
}

// ---------------- per-head weight transpose: Wt[h][i][k] = W[h*512+k][i] ----------------
// grid (8,8,16): x=k-tile, y=i-tile, z = h + 8*(0:Wq,1:Wk). 64x64 LDS tiles.
__global__ __launch_bounds__(256) void wtrans_kernel(
    const unsigned short* __restrict__ Wq, const unsigned short* __restrict__ Wk,
    unsigned short* __restrict__ Wqt, unsigned short* __restrict__ Wkt)
{
  __shared__ unsigned short t[64][72];
  const int k0 = blockIdx.x * 64;
  const int i0 = blockIdx.y * 64;
  const int hz = blockIdx.z;
  const int h = hz & 7;
  const unsigned short* src = (hz < 8) ? Wq : Wk;
  unsigned short* dst = (hz < 8) ? Wqt : Wkt;
  const int tid = threadIdx.x;
  const int r = tid >> 2, c16 = (tid & 3) * 16;
  const unsigned short* sp = src + (size_t)(h * 512 + k0 + r) * 512 + i0 + c16;
  u16x8 v0 = *(const u16x8*)sp;
  u16x8 v1 = *(const u16x8*)(sp + 8);
#pragma unroll
  for (int j = 0; j < 8; ++j) { t[r][c16 + j] = v0[j]; t[r][c16 + 8 + j] = v1[j]; }
  __syncthreads();
  unsigned short o[16];
#pragma unroll
  for (int j = 0; j < 16; ++j) o[j] = t[c16 + j][r];
  unsigned short* dp = dst + (size_t)h * 262144 + (size_t)(i0 + r) * 512 + k0 + c16;
  *(u16x8*)dp = *(u16x8*)o;
  *(u16x8*)(dp + 8) = *(u16x8*)(o + 8);
}

// ---------------- split-K reduce: out = sum(partials) + bias ----------------
__global__ __launch_bounds__(256) void reduce_kernel(
    const float* __restrict__ P, const float* __restrict__ bias,
    float* __restrict__ out)
{
  const int i = blockIdx.x * 256 + threadIdx.x;
  const int col4 = i & 127;
  const float4* p4 = (const float4*)P + i;
  float4 s = p4[0];
#pragma unroll
  for (int z = 1; z < 8; ++z) {
    float4 v = p4[(size_t)z * 524288];
    s.x += v.x; s.y += v.y; s.z += v.z; s.w += v.w;
  }
  float4 b = ((const float4*)bias)[col4];
  s.x += b.x; s.y += b.y; s.z += b.z; s.w += b.w;
  ((float4*)out)[i] = s;
}

// ---------------- fused fp32 -> bf16 cast of all 5 tensors ----------------
__global__ __launch_bounds__(256) void cast5_kernel(
    const float* __restrict__ s0, const float* __restrict__ s1,
    const float* __restrict__ s2, const float* __restrict__ s3,
    const float* __restrict__ s4, unsigned short* __restrict__ dst)
{
  const int seg = blockIdx.x >> 11;
  const int off = (blockIdx.x & 2047) * 256 + threadIdx.x;
  const float* s = s0;
  if (seg == 1) s = s1; else if (seg == 2) s = s2;
  else if (seg == 3) s = s3; else if (seg == 4) s = s4;
  float4 v = ((const float4*)s)[off];
  ushort4 o;
  o.x = f2bf(v.x); o.y = f2bf(v.y); o.z = f2bf(v.z); o.w = f2bf(v.w);
  ((ushort4*)dst)[(size_t)seg * 524288 + off] = o;
}

// ---------------- in-place row softmax over S (bf16), logit = S - mask ----------------
__global__ __launch_bounds__(256) void softmax_kernel(
    unsigned short* __restrict__ S, const float* __restrict__ mask)
{
  const int wave = threadIdx.x >> 6;
  const int lane = threadIdx.x & 63;
  const long long row = (long long)blockIdx.x * 4 + wave;   // 0..32767
  const int q = (int)(row & 1023);
  const int b = (int)(row >> 13);
  unsigned short* Srow = S + row * 1024;
  const float* mrow = mask + ((size_t)b * 1024 + q) * 1024;

  u16x8 sv0 = ((const u16x8*)Srow)[lane * 2];
  u16x8 sv1 = ((const u16x8*)Srow)[lane * 2 + 1];
  float mk[16];
  const float4* m4 = (const float4*)mrow + lane * 4;
#pragma unroll
  for (int t = 0; t < 4; ++t) {
    float4 v = m4[t];
    mk[t * 4 + 0] = v.x; mk[t * 4 + 1] = v.y; mk[t * 4 + 2] = v.z; mk[t * 4 + 3] = v.w;
  }

  float lg[16];
#pragma unroll
  for (int j = 0; j < 8; ++j) lg[j] = bf2f(sv0[j]) - mk[j];
#pragma unroll
  for (int j = 0; j < 8; ++j) lg[8 + j] = bf2f(sv1[j]) - mk[8 + j];

  float mx = lg[0];
#pragma unroll
  for (int j = 1; j < 16; ++j) mx = fmaxf(mx, lg[j]);
#pragma unroll
  for (int off = 32; off > 0; off >>= 1) mx = fmaxf(mx, __shfl_xor(mx, off));

  float ex[16], sm = 0.f;
#pragma unroll
  for (int j = 0; j < 16; ++j) { ex[j] = __expf(lg[j] - mx); sm += ex[j]; }
#pragma unroll
  for (int off = 32; off > 0; off >>= 1) sm += __shfl_xor(sm, off);
  const float rinv = 1.0f / sm;

  u16x8 o0, o1;
#pragma unroll
  for (int j = 0; j < 8; ++j) o0[j] = f2bf(ex[j] * rinv);
#pragma unroll
  for (int j = 0; j < 8; ++j) o1[j] = f2bf(ex[8 + j] * rinv);
  ((u16x8*)Srow)[lane * 2] = o0;
  ((u16x8*)Srow)[lane * 2 + 1] = o1;
}

extern "C" void kernel_launch(void* const* d_in, const int* in_sizes, int n_in,
                              void* d_out, int out_size, void* d_ws, size_t ws_size,
                              hipStream_t stream) {
  const float* x    = (const float*)d_in[0];
  const float* mask = (const float*)d_in[1];
  const float* Wk   = (const float*)d_in[2];
  const float* Wq   = (const float*)d_in[3];
  const float* Wv   = (const float*)d_in[4];
  const float* Wu   = (const float*)d_in[5];
  const float* bu   = (const float*)d_in[6];

  const size_t MB = 1024 * 1024;
  if (ws_size < 192 * MB) return;
  char* ws = (char*)d_ws;
  unsigned short* xb  = (unsigned short*)(ws + 0 * MB);    // 4MB  [4096,512]
  unsigned short* Wqb = (unsigned short*)(ws + 4 * MB);
  unsigned short* Wkb = (unsigned short*)(ws + 8 * MB);
  unsigned short* Wvb = (unsigned short*)(ws + 12 * MB);
  unsigned short* Wub = (unsigned short*)(ws + 16 * MB);
  unsigned short* Wqt = (unsigned short*)(ws + 20 * MB);   // 4MB [h][i][k]
  unsigned short* Wkt = (unsigned short*)(ws + 24 * MB);   // 4MB [h][i][k]
  unsigned short* Nh  = (unsigned short*)(ws + 28 * MB);   // 4MB [h][512][512] = M_h^T
  unsigned short* xM  = (unsigned short*)(ws + 32 * MB);   // 32MB [b,t,h,j] (Q-like)
  unsigned short* Vt  = (unsigned short*)(ws + 64 * MB);   // 32MB [h*e, b*t]
  unsigned short* Sb  = (unsigned short*)(ws + 96 * MB);   // 64MB [b,h,q,k]
  unsigned short* Ob  = (unsigned short*)(ws + 160 * MB);  // 32MB [b,t,h*e]
  float* Pk = (float*)(ws + 96 * MB);  // split-K partials overlay Sb (dead post-PV)

  cast5_kernel<<<5 * 2048, 256, 0, stream>>>(x, Wq, Wk, Wv, Wu, xb);

  // per-head transposes of Wq, Wk
  wtrans_kernel<<<dim3(8, 8, 16), 256, 0, stream>>>(Wqb, Wkb, Wqt, Wkt);

  // N_h = Wkt_h . Wqt_h^T  (= (Wq_h^T Wk_h)^T), 8 batched 512^3
  gemm_bt2<unsigned short><<<dim3(2, 2, 8), 512, 0, stream>>>(
      Wkt, Wqt, Nh,
      512, 512, 512, 512, 0,
      262144LL, 0, 262144LL, 0, 262144LL, 0, 1.0f);

  // xM = x . M_h  (BT with B = N_h = M^T): out col-block h*512 in [4096,4096]
  gemm_bt2<unsigned short><<<dim3(2, 16, 8), 512, 0, stream>>>(
      xb, Nh, xM,
      512, 512, 512, 4096, 0,
      0, 0, 262144LL, 0, 512LL, 0, 1.0f);

  // Vt = Wv . x^T
  gemm_bt2<unsigned short><<<dim3(16, 16, 1), 512, 0, stream>>>(
      Wvb, xb, Vt,
      512, 512, 512, 4096, 0,
      0, 0, 0, 0, 0, 0, 1.0f);

  // S = a * xM_{b,h} . x_b^T   (M=N=1024, K=512, 32 batches; B depends on b only)
  gemm_bt2<unsigned short><<<dim3(4, 4, 32), 512, 0, stream>>>(
      xM, xb, Sb,
      512, 4096, 512, 1024, 3,
      4194304LL, 512LL, 524288LL, 0, 8388608LL, 1048576LL,
      0.044194173824159216f);

  // P = softmax(S - mask) in place
  softmax_kernel<<<8192, 256, 0, stream>>>(Sb, mask);

  // O = P.V   (M=1024, N=512, K=1024, 32 batches)
  gemm_bt2<unsigned short><<<dim3(2, 4, 32), 512, 0, stream>>>(
      Sb, Vt, Ob,
      1024, 1024, 4096, 4096, 3,
      8388608LL, 1048576LL, 1024LL, 2097152LL, 4194304LL, 512LL, 1.0f);

  // out partials: split-K=8 over K=4096 (M=4096, N=512, slice=512)
  gemm_bt2<float><<<dim3(2, 16, 8), 512, 0, stream>>>(
      Ob, Wub, Pk,
      512, 4096, 4096, 512, 0,
      512LL, 0, 512LL, 0, 2097152LL, 0, 1.0f);

  // out = sum_z Pk[z] + bu
  reduce_kernel<<<2048, 256, 0, stream>>>(Pk, bu, (float*)d_out);
}

// Round 19
// 224.693 us; speedup vs baseline: 1.2346x; 1.0787x over previous
//
#include <hip/hip_runtime.h>
#include <hip/hip_bf16.h>

// B=4, T=1024, E=512, H=8. Two-pass attention, BOTH-SIDES ALGEBRAIC REWRITE:
//   input side:  S_h = x.(Wq_h^T Wk_h).x^T  -> Nh + xM  (R18, kept)
//   output side: out = sum_h P_h.(x.G_h^T) + bu, G_h = Wu_h.Wv_h  (NEW)
//     -> Vt/PV/outGEMM (68.8 GF) replaced by Gh (2.1) + xGt (17.2) + PxG (34.4).
//     PxG writes 8 per-head fp32 partials -> existing reduce(+bias) sums them.
// Pipeline: cast5 -> wtrans(Wq,Wk,Wv) -> {Nh|Gh} merged dual-config dispatch
//   -> xM -> xGt (=G.x^T, pre-transposed) -> S = xM.x^T*a -> softmax
//   -> PxG (per-head partials) -> reduce(+bias).
// gemm_bt2 core (R12/R16-proven, UNCHANGED schedule): 256x256, BK=32,
// 512thr/8w, 3-buf counted-vmcnt, T5 setprio, T1 bijective XCD swizzle.
// Dual-config: selGE>=0 && hh>=selGE -> (A2,B2,C2,lda2) with h2=hh-selGE
// (R16 vtSel mechanism, generalized to lda) -- merges Nh+Gh small GEMMs.
// MEASURED LAWS (R5-R18): (512,1) no spill; rate pins at ~550-600 TF across
// all schedule/tile variants (m233 ceiling) -> optimize FLOPs, not rate.
// Layouts: xM [b,t,h,j] ld 4096; xGt [h*512+i][b*1024+k] ld 4096;
//   S/P [b,h,q,k]; Wqt/Wkt/Wvt [h][i][k]; Nh/Gh [h][512][512];
//   Pk = 8 x [4096,512] fp32 partials (overlay, dead-region audited).

typedef short bf16x8 __attribute__((ext_vector_type(8)));
typedef float f32x4 __attribute__((ext_vector_type(4)));
typedef unsigned short u16x8 __attribute__((ext_vector_type(8)));

__device__ __forceinline__ unsigned short f2bf(float f) {
  unsigned int u = __float_as_uint(f);
  u += 0x7FFFu + ((u >> 16) & 1u);            // RNE, finite inputs
  return (unsigned short)(u >> 16);
}
__device__ __forceinline__ float bf2f(unsigned short s) {
  return __uint_as_float(((unsigned int)s) << 16);
}

typedef const __attribute__((address_space(1))) unsigned int* gas1_t;
typedef __attribute__((address_space(3))) unsigned int* las3_t;

__device__ __forceinline__ void gload16(const unsigned short* g, unsigned short* l) {
  __builtin_amdgcn_global_load_lds((gas1_t)g, (las3_t)l, 16, 0, 0);
}

__device__ __forceinline__ void store_val(unsigned short* p, float v) { *p = f2bf(v); }
__device__ __forceinline__ void store_val(float* p, float v) { *p = v; }

// ---------------- 256x256-tile BT GEMM, BK=32, 3-buf counted-vmcnt ----------------
template<typename OutT>
__global__ __launch_bounds__(512, 1) void gemm_bt2(
    const unsigned short* __restrict__ A, const unsigned short* __restrict__ B,
    OutT* __restrict__ C,
    int K, int lda, int ldb, int ldc, int zshift,
    long long sAb, long long sAh, long long sBb, long long sBh,
    long long sCb, long long sCh, float alpha,
    const unsigned short* __restrict__ A2, const unsigned short* __restrict__ B2,
    OutT* __restrict__ C2, int lda2,
    long long sA2h, long long sB2h, long long sC2h, int selGE)
{
  const int tid  = threadIdx.x;
  const int lane = tid & 63;
  const int wave = tid >> 6;
  const int l15 = lane & 15, lhi = lane >> 4;
  const int wm = wave >> 2, wn = wave & 3;           // 2M x 4N wave grid

  const int nx = gridDim.x, nxy = gridDim.x * gridDim.y;
  const int nwg = nxy * gridDim.z;
  int flat = blockIdx.x + nx * blockIdx.y + nxy * blockIdx.z;
  flat = (flat & 7) * (nwg >> 3) + (flat >> 3);
  const int bz = flat / nxy;
  const int rem = flat - bz * nxy;
  const int by = rem / nx;
  const int bx = rem - by * nx;

  const int bb = bz >> zshift, hh = bz & ((1 << zshift) - 1);
  const long long m0 = (long long)by * 256;
  const long long n0 = (long long)bx * 256;

  const unsigned short* Ab;
  const unsigned short* Bb;
  OutT* Cb;
  int ldaU = lda;
  if (selGE >= 0 && hh >= selGE) {
    const int h2 = hh - selGE;
    Ab = A2 + (size_t)h2 * sA2h;
    Bb = B2 + (size_t)h2 * sB2h;
    Cb = C2 + (size_t)h2 * sC2h;
    ldaU = lda2;
  } else {
    Ab = A + bb * sAb + hh * sAh;
    Bb = B + bb * sBb + hh * sBh;
    Cb = C + bb * sCb + hh * sCh;
  }

  __shared__ __align__(16) unsigned short lds[49152];  // 96 KB, 3 buffers

  const unsigned short* gA[2];
  const unsigned short* gB[2];
  int fidx[2];
#pragma unroll
  for (int c = 0; c < 2; ++c) {
    const int f = c * 8 + wave;
    fidx[c] = f;
    gA[c] = Ab + (size_t)(m0 + f * 16 + l15) * ldaU + lhi * 8;
    gB[c] = Bb + (size_t)(n0 + f * 16 + l15) * ldb + lhi * 8;
  }

  auto stage = [&](int n, int p) {
    unsigned short* dst = lds + p * 16384;
    const int ko = n * 32;
#pragma unroll
    for (int c = 0; c < 2; ++c) {
      gload16(gA[c] + ko, dst + fidx[c] * 512);
      gload16(gB[c] + ko, dst + 8192 + fidx[c] * 512);
    }
  };

  f32x4 acc[8][4];
#pragma unroll
  for (int m = 0; m < 8; ++m)
#pragma unroll
    for (int n = 0; n < 4; ++n) acc[m][n] = (f32x4){0.f, 0.f, 0.f, 0.f};

  const int nt = K >> 5;
  stage(0, 0);
  stage(1, 1);
  asm volatile("s_waitcnt vmcnt(4)" ::: "memory");
  __builtin_amdgcn_sched_barrier(0);
  __builtin_amdgcn_s_barrier();

  for (int t = 0; t < nt; ++t) {
    const bool pref = (t + 2 < nt);
    if (pref) stage(t + 2, (t + 2) % 3);
    const unsigned short* base = lds + (t % 3) * 16384;
    bf16x8 af[8], bf[4];
#pragma unroll
    for (int mf = 0; mf < 8; ++mf)
      af[mf] = *(const bf16x8*)(base + (wm * 8 + mf) * 512 + lane * 8);
#pragma unroll
    for (int nf = 0; nf < 4; ++nf)
      bf[nf] = *(const bf16x8*)(base + 8192 + (wn * 4 + nf) * 512 + lane * 8);
    __builtin_amdgcn_s_setprio(1);
#pragma unroll
    for (int mf = 0; mf < 8; ++mf)
#pragma unroll
      for (int nf = 0; nf < 4; ++nf)
        acc[mf][nf] = __builtin_amdgcn_mfma_f32_16x16x32_bf16(af[mf], bf[nf], acc[mf][nf], 0, 0, 0);
    __builtin_amdgcn_s_setprio(0);
    if (pref) asm volatile("s_waitcnt vmcnt(4)" ::: "memory");
    else      asm volatile("s_waitcnt vmcnt(0)" ::: "memory");
    __builtin_amdgcn_sched_barrier(0);
    __builtin_amdgcn_s_barrier();
    __builtin_amdgcn_sched_barrier(0);
  }

  // C/D layout (m89/m91): col = lane&15, row = (lane>>4)*4 + reg
#pragma unroll
  for (int mf = 0; mf < 8; ++mf) {
#pragma unroll
    for (int nf = 0; nf < 4; ++nf) {
      const long long col = n0 + wn * 64 + nf * 16 + l15;
#pragma unroll
      for (int r = 0; r < 4; ++r) {
        const long long row = m0 + wm * 128 + mf * 16 + lhi * 4 + r;
        store_val(Cb + (size_t)row * ldc + col, acc[mf][nf][r] * alpha);
      }
    }
  }
}

// ---------------- per-head weight transpose: Wt[h][i][k] = W[h*512+k][i] ----------------
// grid (8,8,24): x=k-tile, y=i-tile, z = h + 8*{0:Wq,1:Wk,2:Wv}. 64x64 LDS tiles.
__global__ __launch_bounds__(256) void wtrans_kernel(
    const unsigned short* __restrict__ Wq, const unsigned short* __restrict__ Wk,
    const unsigned short* __restrict__ Wv,
    unsigned short* __restrict__ Wqt, unsigned short* __restrict__ Wkt,
    unsigned short* __restrict__ Wvt)
{
  __shared__ unsigned short t[64][72];
  const int k0 = blockIdx.x * 64;
  const int i0 = blockIdx.y * 64;
  const int hz = blockIdx.z;
  const int h = hz & 7;
  const int w = hz >> 3;
  const unsigned short* src = (w == 0) ? Wq : ((w == 1) ? Wk : Wv);
  unsigned short* dst = (w == 0) ? Wqt : ((w == 1) ? Wkt : Wvt);
  const int tid = threadIdx.x;
  const int r = tid >> 2, c16 = (tid & 3) * 16;
  const unsigned short* sp = src + (size_t)(h * 512 + k0 + r) * 512 + i0 + c16;
  u16x8 v0 = *(const u16x8*)sp;
  u16x8 v1 = *(const u16x8*)(sp + 8);
#pragma unroll
  for (int j = 0; j < 8; ++j) { t[r][c16 + j] = v0[j]; t[r][c16 + 8 + j] = v1[j]; }
  __syncthreads();
  unsigned short o[16];
#pragma unroll
  for (int j = 0; j < 16; ++j) o[j] = t[c16 + j][r];
  unsigned short* dp = dst + (size_t)h * 262144 + (size_t)(i0 + r) * 512 + k0 + c16;
  *(u16x8*)dp = *(u16x8*)o;
  *(u16x8*)(dp + 8) = *(u16x8*)(o + 8);
}

// ---------------- 8-way partial reduce: out = sum_z(partials) + bias ----------------
__global__ __launch_bounds__(256) void reduce_kernel(
    const float* __restrict__ P, const float* __restrict__ bias,
    float* __restrict__ out)
{
  const int i = blockIdx.x * 256 + threadIdx.x;
  const int col4 = i & 127;
  const float4* p4 = (const float4*)P + i;
  float4 s = p4[0];
#pragma unroll
  for (int z = 1; z < 8; ++z) {
    float4 v = p4[(size_t)z * 524288];
    s.x += v.x; s.y += v.y; s.z += v.z; s.w += v.w;
  }
  float4 b = ((const float4*)bias)[col4];
  s.x += b.x; s.y += b.y; s.z += b.z; s.w += b.w;
  ((float4*)out)[i] = s;
}

// ---------------- fused fp32 -> bf16 cast of all 5 tensors ----------------
__global__ __launch_bounds__(256) void cast5_kernel(
    const float* __restrict__ s0, const float* __restrict__ s1,
    const float* __restrict__ s2, const float* __restrict__ s3,
    const float* __restrict__ s4, unsigned short* __restrict__ dst)
{
  const int seg = blockIdx.x >> 11;
  const int off = (blockIdx.x & 2047) * 256 + threadIdx.x;
  const float* s = s0;
  if (seg == 1) s = s1; else if (seg == 2) s = s2;
  else if (seg == 3) s = s3; else if (seg == 4) s = s4;
  float4 v = ((const float4*)s)[off];
  ushort4 o;
  o.x = f2bf(v.x); o.y = f2bf(v.y); o.z = f2bf(v.z); o.w = f2bf(v.w);
  ((ushort4*)dst)[(size_t)seg * 524288 + off] = o;
}

// ---------------- in-place row softmax over S (bf16), logit = S - mask ----------------
__global__ __launch_bounds__(256) void softmax_kernel(
    unsigned short* __restrict__ S, const float* __restrict__ mask)
{
  const int wave = threadIdx.x >> 6;
  const int lane = threadIdx.x & 63;
  const long long row = (long long)blockIdx.x * 4 + wave;   // 0..32767
  const int q = (int)(row & 1023);
  const int b = (int)(row >> 13);
  unsigned short* Srow = S + row * 1024;
  const float* mrow = mask + ((size_t)b * 1024 + q) * 1024;

  u16x8 sv0 = ((const u16x8*)Srow)[lane * 2];
  u16x8 sv1 = ((const u16x8*)Srow)[lane * 2 + 1];
  float mk[16];
  const float4* m4 = (const float4*)mrow + lane * 4;
#pragma unroll
  for (int t = 0; t < 4; ++t) {
    float4 v = m4[t];
    mk[t * 4 + 0] = v.x; mk[t * 4 + 1] = v.y; mk[t * 4 + 2] = v.z; mk[t * 4 + 3] = v.w;
  }

  float lg[16];
#pragma unroll
  for (int j = 0; j < 8; ++j) lg[j] = bf2f(sv0[j]) - mk[j];
#pragma unroll
  for (int j = 0; j < 8; ++j) lg[8 + j] = bf2f(sv1[j]) - mk[8 + j];

  float mx = lg[0];
#pragma unroll
  for (int j = 1; j < 16; ++j) mx = fmaxf(mx, lg[j]);
#pragma unroll
  for (int off = 32; off > 0; off >>= 1) mx = fmaxf(mx, __shfl_xor(mx, off));

  float ex[16], sm = 0.f;
#pragma unroll
  for (int j = 0; j < 16; ++j) { ex[j] = __expf(lg[j] - mx); sm += ex[j]; }
#pragma unroll
  for (int off = 32; off > 0; off >>= 1) sm += __shfl_xor(sm, off);
  const float rinv = 1.0f / sm;

  u16x8 o0, o1;
#pragma unroll
  for (int j = 0; j < 8; ++j) o0[j] = f2bf(ex[j] * rinv);
#pragma unroll
  for (int j = 0; j < 8; ++j) o1[j] = f2bf(ex[8 + j] * rinv);
  ((u16x8*)Srow)[lane * 2] = o0;
  ((u16x8*)Srow)[lane * 2 + 1] = o1;
}

extern "C" void kernel_launch(void* const* d_in, const int* in_sizes, int n_in,
                              void* d_out, int out_size, void* d_ws, size_t ws_size,
                              hipStream_t stream) {
  const float* x    = (const float*)d_in[0];
  const float* mask = (const float*)d_in[1];
  const float* Wk   = (const float*)d_in[2];
  const float* Wq   = (const float*)d_in[3];
  const float* Wv   = (const float*)d_in[4];
  const float* Wu   = (const float*)d_in[5];
  const float* bu   = (const float*)d_in[6];

  const size_t MB = 1024 * 1024;
  if (ws_size < 192 * MB) return;
  char* ws = (char*)d_ws;
  unsigned short* xb  = (unsigned short*)(ws + 0 * MB);    // 4MB  [4096,512]
  unsigned short* Wqb = (unsigned short*)(ws + 4 * MB);
  unsigned short* Wkb = (unsigned short*)(ws + 8 * MB);
  unsigned short* Wvb = (unsigned short*)(ws + 12 * MB);
  unsigned short* Wub = (unsigned short*)(ws + 16 * MB);
  unsigned short* Wqt = (unsigned short*)(ws + 20 * MB);   // 4MB [h][i][k]
  unsigned short* Wkt = (unsigned short*)(ws + 24 * MB);   // 4MB
  unsigned short* Wvt = (unsigned short*)(ws + 28 * MB);   // 4MB
  unsigned short* Nh  = (unsigned short*)(ws + 32 * MB);   // 4MB [h][512][512]
  unsigned short* Gh  = (unsigned short*)(ws + 36 * MB);   // 4MB [h][512][512]
  unsigned short* xM  = (unsigned short*)(ws + 40 * MB);   // 32MB [b,t,h,j]
  unsigned short* xGt = (unsigned short*)(ws + 72 * MB);   // 32MB [h*512+i][b*1024+k]
  unsigned short* Sb  = (unsigned short*)(ws + 104 * MB);  // 64MB [b,h,q,k]
  // Pk: 8 x [4096,512] fp32 = 64MB, overlays ws[4..68) (Wqb..Wub, W*t, Nh, Gh,
  // xM -- ALL dead by PxG time; xb at [0,4) and xGt/Sb untouched).
  float* Pk = (float*)(ws + 4 * MB);

  cast5_kernel<<<5 * 2048, 256, 0, stream>>>(x, Wq, Wk, Wv, Wu, xb);

  // per-head transposes of Wq, Wk, Wv
  wtrans_kernel<<<dim3(8, 8, 24), 256, 0, stream>>>(Wqb, Wkb, Wvb, Wqt, Wkt, Wvt);

  // merged small-GEMM dispatch (64 blocks): hh<8: Nh_h = Wkt_h.Wqt_h^T;
  // hh>=8 (h2=hh-8): Gh_h2 = Wu_h2 . Wvt_h2^T  (A=Wub col-slice, lda 4096)
  gemm_bt2<unsigned short><<<dim3(2, 2, 16), 512, 0, stream>>>(
      Wkt, Wqt, Nh,
      512, 512, 512, 512, 4,
      0, 262144LL, 0, 262144LL, 0, 262144LL, 1.0f,
      Wub, Wvt, Gh, 4096, 512LL, 262144LL, 262144LL, 8);

  // xM = x . M_h (B = Nh = M^T), out col-block h*512 in [4096,4096]
  gemm_bt2<unsigned short><<<dim3(2, 16, 8), 512, 0, stream>>>(
      xb, Nh, xM,
      512, 512, 512, 4096, 0,
      0, 0, 262144LL, 0, 512LL, 0, 1.0f,
      nullptr, nullptr, nullptr, 0, 0, 0, 0, -1);

  // xGt = Gh_stack . x^T  (M=4096 (h,i), N=4096 (b,k), K=512)
  gemm_bt2<unsigned short><<<dim3(16, 16, 1), 512, 0, stream>>>(
      Gh, xb, xGt,
      512, 512, 512, 4096, 0,
      0, 0, 0, 0, 0, 0, 1.0f,
      nullptr, nullptr, nullptr, 0, 0, 0, 0, -1);

  // S = a * xM_{b,h} . x_b^T   (M=N=1024, K=512, 32 batches)
  gemm_bt2<unsigned short><<<dim3(4, 4, 32), 512, 0, stream>>>(
      xM, xb, Sb,
      512, 4096, 512, 1024, 3,
      4194304LL, 512LL, 524288LL, 0, 8388608LL, 1048576LL,
      0.044194173824159216f,
      nullptr, nullptr, nullptr, 0, 0, 0, 0, -1);

  // P = softmax(S - mask) in place
  softmax_kernel<<<8192, 256, 0, stream>>>(Sb, mask);

  // PxG: out-partial[h][b*1024+q][i] = sum_k P[b,h,q,k] * xGt[h*512+i][b*1024+k]
  gemm_bt2<float><<<dim3(2, 4, 32), 512, 0, stream>>>(
      Sb, xGt, Pk,
      1024, 1024, 4096, 512, 3,
      8388608LL, 1048576LL, 1024LL, 2097152LL, 524288LL, 2097152LL, 1.0f,
      nullptr, nullptr, nullptr, 0, 0, 0, 0, -1);

  // out = sum_h Pk[h] + bu
  reduce_kernel<<<2048, 256, 0, stream>>>(Pk, bu, (float*)d_out);
}

// Round 20
// 217.535 us; speedup vs baseline: 1.2752x; 1.0329x over previous
//
#include <hip/hip_runtime.h>
#include <hip/hip_bf16.h>

// B=4, T=1024, E=512, H=8. Both-sides algebraic rewrite (R18+R19, kept):
//   S_h = x.(Wq_h^T Wk_h).x^T ; out = sum_h P_h.(x.G_h^T)+bu, G_h=Wu_h.Wv_h.
// GEMM work: NhGh 4.3 + xM 17.2 + xGt 17.2 + S 34.4 + PxG 34.4 = 107.5 GF.
// R20: non-GEMM trims -- (1) softmax: one block per (b,q), 8 waves = 8 heads,
// mask row read once (was 8x); (2) wtrans reads fp32 W directly (cast5->cast2);
// (3) xM+xGt merged into one dual-config dispatch (m0/n0 role swap for the
// transposed-output config).
// gemm_bt2 core (R12-proven, UNCHANGED): 256x256, BK=32, 512thr/8w, 3-buf
// counted-vmcnt, T5 setprio, T1 bijective XCD swizzle (all grids % 8 == 0).
// MEASURED LAWS (R5-R19): (512,1) no spill; rate pins at ~550-600 TF across
// all schedule/tile variants (m233 2-phase ceiling) -> optimize FLOPs/overhead.
// Layouts: xM [b,t,h,j] ld 4096; xGt [h*512+i][b*1024+k] ld 4096;
//   S/P [b,h,q,k]; Wqt/Wkt/Wvt [h][i][k]; Nh/Gh [h][512][512];
//   Pk = 8 x [4096,512] fp32 partials (overlays dead weights/xM, audited).

typedef short bf16x8 __attribute__((ext_vector_type(8)));
typedef float f32x4 __attribute__((ext_vector_type(4)));
typedef unsigned short u16x8 __attribute__((ext_vector_type(8)));

__device__ __forceinline__ unsigned short f2bf(float f) {
  unsigned int u = __float_as_uint(f);
  u += 0x7FFFu + ((u >> 16) & 1u);            // RNE, finite inputs
  return (unsigned short)(u >> 16);
}
__device__ __forceinline__ float bf2f(unsigned short s) {
  return __uint_as_float(((unsigned int)s) << 16);
}

typedef const __attribute__((address_space(1))) unsigned int* gas1_t;
typedef __attribute__((address_space(3))) unsigned int* las3_t;

__device__ __forceinline__ void gload16(const unsigned short* g, unsigned short* l) {
  __builtin_amdgcn_global_load_lds((gas1_t)g, (las3_t)l, 16, 0, 0);
}

__device__ __forceinline__ void store_val(unsigned short* p, float v) { *p = f2bf(v); }
__device__ __forceinline__ void store_val(float* p, float v) { *p = v; }

// ---------------- 256x256-tile BT GEMM, BK=32, 3-buf counted-vmcnt ----------------
// Dual-config: selGE>=0 && hh>=selGE -> (A2,B2,C2,lda2), h2=hh-selGE, and
// m0/n0 roles SWAPPED (supports transposed-shape second config).
template<typename OutT>
__global__ __launch_bounds__(512, 1) void gemm_bt2(
    const unsigned short* __restrict__ A, const unsigned short* __restrict__ B,
    OutT* __restrict__ C,
    int K, int lda, int ldb, int ldc, int zshift,
    long long sAb, long long sAh, long long sBb, long long sBh,
    long long sCb, long long sCh, float alpha,
    const unsigned short* __restrict__ A2, const unsigned short* __restrict__ B2,
    OutT* __restrict__ C2, int lda2,
    long long sA2h, long long sB2h, long long sC2h, int selGE)
{
  const int tid  = threadIdx.x;
  const int lane = tid & 63;
  const int wave = tid >> 6;
  const int l15 = lane & 15, lhi = lane >> 4;
  const int wm = wave >> 2, wn = wave & 3;           // 2M x 4N wave grid

  const int nx = gridDim.x, nxy = gridDim.x * gridDim.y;
  const int nwg = nxy * gridDim.z;
  int flat = blockIdx.x + nx * blockIdx.y + nxy * blockIdx.z;
  flat = (flat & 7) * (nwg >> 3) + (flat >> 3);
  const int bz = flat / nxy;
  const int rem = flat - bz * nxy;
  const int by = rem / nx;
  const int bx = rem - by * nx;

  const int bb = bz >> zshift, hh = bz & ((1 << zshift) - 1);

  const unsigned short* Ab;
  const unsigned short* Bb;
  OutT* Cb;
  int ldaU = lda;
  long long m0, n0;
  if (selGE >= 0 && hh >= selGE) {
    const int h2 = hh - selGE;
    Ab = A2 + (size_t)h2 * sA2h;
    Bb = B2 + (size_t)h2 * sB2h;
    Cb = C2 + (size_t)h2 * sC2h;
    ldaU = lda2;
    m0 = (long long)bx * 256;                        // swapped roles
    n0 = (long long)by * 256;
  } else {
    Ab = A + bb * sAb + hh * sAh;
    Bb = B + bb * sBb + hh * sBh;
    Cb = C + bb * sCb + hh * sCh;
    m0 = (long long)by * 256;
    n0 = (long long)bx * 256;
  }

  __shared__ __align__(16) unsigned short lds[49152];  // 96 KB, 3 buffers

  const unsigned short* gA[2];
  const unsigned short* gB[2];
  int fidx[2];
#pragma unroll
  for (int c = 0; c < 2; ++c) {
    const int f = c * 8 + wave;
    fidx[c] = f;
    gA[c] = Ab + (size_t)(m0 + f * 16 + l15) * ldaU + lhi * 8;
    gB[c] = Bb + (size_t)(n0 + f * 16 + l15) * ldb + lhi * 8;
  }

  auto stage = [&](int n, int p) {
    unsigned short* dst = lds + p * 16384;
    const int ko = n * 32;
#pragma unroll
    for (int c = 0; c < 2; ++c) {
      gload16(gA[c] + ko, dst + fidx[c] * 512);
      gload16(gB[c] + ko, dst + 8192 + fidx[c] * 512);
    }
  };

  f32x4 acc[8][4];
#pragma unroll
  for (int m = 0; m < 8; ++m)
#pragma unroll
    for (int n = 0; n < 4; ++n) acc[m][n] = (f32x4){0.f, 0.f, 0.f, 0.f};

  const int nt = K >> 5;
  stage(0, 0);
  stage(1, 1);
  asm volatile("s_waitcnt vmcnt(4)" ::: "memory");
  __builtin_amdgcn_sched_barrier(0);
  __builtin_amdgcn_s_barrier();

  for (int t = 0; t < nt; ++t) {
    const bool pref = (t + 2 < nt);
    if (pref) stage(t + 2, (t + 2) % 3);
    const unsigned short* base = lds + (t % 3) * 16384;
    bf16x8 af[8], bf[4];
#pragma unroll
    for (int mf = 0; mf < 8; ++mf)
      af[mf] = *(const bf16x8*)(base + (wm * 8 + mf) * 512 + lane * 8);
#pragma unroll
    for (int nf = 0; nf < 4; ++nf)
      bf[nf] = *(const bf16x8*)(base + 8192 + (wn * 4 + nf) * 512 + lane * 8);
    __builtin_amdgcn_s_setprio(1);
#pragma unroll
    for (int mf = 0; mf < 8; ++mf)
#pragma unroll
      for (int nf = 0; nf < 4; ++nf)
        acc[mf][nf] = __builtin_amdgcn_mfma_f32_16x16x32_bf16(af[mf], bf[nf], acc[mf][nf], 0, 0, 0);
    __builtin_amdgcn_s_setprio(0);
    if (pref) asm volatile("s_waitcnt vmcnt(4)" ::: "memory");
    else      asm volatile("s_waitcnt vmcnt(0)" ::: "memory");
    __builtin_amdgcn_sched_barrier(0);
    __builtin_amdgcn_s_barrier();
    __builtin_amdgcn_sched_barrier(0);
  }

  // C/D layout (m89/m91): col = lane&15, row = (lane>>4)*4 + reg
#pragma unroll
  for (int mf = 0; mf < 8; ++mf) {
#pragma unroll
    for (int nf = 0; nf < 4; ++nf) {
      const long long col = n0 + wn * 64 + nf * 16 + l15;
#pragma unroll
      for (int r = 0; r < 4; ++r) {
        const long long row = m0 + wm * 128 + mf * 16 + lhi * 4 + r;
        store_val(Cb + (size_t)row * ldc + col, acc[mf][nf][r] * alpha);
      }
    }
  }
}

// ---------------- per-head transpose + cast: Wt[h][i][k] = bf16(W[h*512+k][i]) ----------------
// Reads fp32 W directly. grid (8,8,24): x=k-tile, y=i-tile, z=h+8*{0:Wq,1:Wk,2:Wv}.
__global__ __launch_bounds__(256) void wtrans_kernel(
    const float* __restrict__ Wq, const float* __restrict__ Wk,
    const float* __restrict__ Wv,
    unsigned short* __restrict__ Wqt, unsigned short* __restrict__ Wkt,
    unsigned short* __restrict__ Wvt)
{
  __shared__ unsigned short t[64][72];
  const int k0 = blockIdx.x * 64;
  const int i0 = blockIdx.y * 64;
  const int hz = blockIdx.z;
  const int h = hz & 7;
  const int w = hz >> 3;
  const float* src = (w == 0) ? Wq : ((w == 1) ? Wk : Wv);
  unsigned short* dst = (w == 0) ? Wqt : ((w == 1) ? Wkt : Wvt);
  const int tid = threadIdx.x;
  const int r = tid >> 2, c16 = (tid & 3) * 16;
  const float* sp = src + (size_t)(h * 512 + k0 + r) * 512 + i0 + c16;
#pragma unroll
  for (int g = 0; g < 4; ++g) {
    float4 v = *(const float4*)(sp + g * 4);
    t[r][c16 + g * 4 + 0] = f2bf(v.x);
    t[r][c16 + g * 4 + 1] = f2bf(v.y);
    t[r][c16 + g * 4 + 2] = f2bf(v.z);
    t[r][c16 + g * 4 + 3] = f2bf(v.w);
  }
  __syncthreads();
  unsigned short o[16];
#pragma unroll
  for (int j = 0; j < 16; ++j) o[j] = t[c16 + j][r];
  unsigned short* dp = dst + (size_t)h * 262144 + (size_t)(i0 + r) * 512 + k0 + c16;
  *(u16x8*)dp = *(u16x8*)o;
  *(u16x8*)(dp + 8) = *(u16x8*)(o + 8);
}

// ---------------- 8-way partial reduce: out = sum_h(partials) + bias ----------------
__global__ __launch_bounds__(256) void reduce_kernel(
    const float* __restrict__ P, const float* __restrict__ bias,
    float* __restrict__ out)
{
  const int i = blockIdx.x * 256 + threadIdx.x;
  const int col4 = i & 127;
  const float4* p4 = (const float4*)P + i;
  float4 s = p4[0];
#pragma unroll
  for (int z = 1; z < 8; ++z) {
    float4 v = p4[(size_t)z * 524288];
    s.x += v.x; s.y += v.y; s.z += v.z; s.w += v.w;
  }
  float4 b = ((const float4*)bias)[col4];
  s.x += b.x; s.y += b.y; s.z += b.z; s.w += b.w;
  ((float4*)out)[i] = s;
}

// ---------------- fp32 -> bf16 cast of x and Wu ----------------
__global__ __launch_bounds__(256) void cast2_kernel(
    const float* __restrict__ s0, const float* __restrict__ s1,
    unsigned short* __restrict__ d0, unsigned short* __restrict__ d1)
{
  const int seg = blockIdx.x >> 11;
  const int off = (blockIdx.x & 2047) * 256 + threadIdx.x;
  const float* s = seg ? s1 : s0;
  unsigned short* d = seg ? d1 : d0;
  float4 v = ((const float4*)s)[off];
  ushort4 o;
  o.x = f2bf(v.x); o.y = f2bf(v.y); o.z = f2bf(v.z); o.w = f2bf(v.w);
  ((ushort4*)d)[off] = o;
}

// ---------------- softmax: one block per (b,q); wave w = head w ----------------
// mask row read once per block (L1 broadcast across 8 waves). S [b,h,q,k] bf16.
__global__ __launch_bounds__(512) void softmax_kernel(
    unsigned short* __restrict__ S, const float* __restrict__ mask)
{
  const int wave = threadIdx.x >> 6;                 // head
  const int lane = threadIdx.x & 63;
  const int bq = blockIdx.x;                         // 0..4095
  const int b = bq >> 10, q = bq & 1023;
  unsigned short* Srow = S + (((size_t)(b * 8 + wave)) * 1024 + q) * 1024;
  const float* mrow = mask + ((size_t)(b * 1024 + q)) * 1024;

  u16x8 sv0 = ((const u16x8*)Srow)[lane * 2];
  u16x8 sv1 = ((const u16x8*)Srow)[lane * 2 + 1];
  float mk[16];
  const float4* m4 = (const float4*)mrow + lane * 4;
#pragma unroll
  for (int t = 0; t < 4; ++t) {
    float4 v = m4[t];
    mk[t * 4 + 0] = v.x; mk[t * 4 + 1] = v.y; mk[t * 4 + 2] = v.z; mk[t * 4 + 3] = v.w;
  }

  float lg[16];
#pragma unroll
  for (int j = 0; j < 8; ++j) lg[j] = bf2f(sv0[j]) - mk[j];
#pragma unroll
  for (int j = 0; j < 8; ++j) lg[8 + j] = bf2f(sv1[j]) - mk[8 + j];

  float mx = lg[0];
#pragma unroll
  for (int j = 1; j < 16; ++j) mx = fmaxf(mx, lg[j]);
#pragma unroll
  for (int off = 32; off > 0; off >>= 1) mx = fmaxf(mx, __shfl_xor(mx, off));

  float ex[16], sm = 0.f;
#pragma unroll
  for (int j = 0; j < 16; ++j) { ex[j] = __expf(lg[j] - mx); sm += ex[j]; }
#pragma unroll
  for (int off = 32; off > 0; off >>= 1) sm += __shfl_xor(sm, off);
  const float rinv = 1.0f / sm;

  u16x8 o0, o1;
#pragma unroll
  for (int j = 0; j < 8; ++j) o0[j] = f2bf(ex[j] * rinv);
#pragma unroll
  for (int j = 0; j < 8; ++j) o1[j] = f2bf(ex[8 + j] * rinv);
  ((u16x8*)Srow)[lane * 2] = o0;
  ((u16x8*)Srow)[lane * 2 + 1] = o1;
}

extern "C" void kernel_launch(void* const* d_in, const int* in_sizes, int n_in,
                              void* d_out, int out_size, void* d_ws, size_t ws_size,
                              hipStream_t stream) {
  const float* x    = (const float*)d_in[0];
  const float* mask = (const float*)d_in[1];
  const float* Wk   = (const float*)d_in[2];
  const float* Wq   = (const float*)d_in[3];
  const float* Wv   = (const float*)d_in[4];
  const float* Wu   = (const float*)d_in[5];
  const float* bu   = (const float*)d_in[6];

  const size_t MB = 1024 * 1024;
  if (ws_size < 192 * MB) return;
  char* ws = (char*)d_ws;
  unsigned short* xb  = (unsigned short*)(ws + 0 * MB);    // 4MB  [4096,512]
  unsigned short* xGt = (unsigned short*)(ws + 4 * MB);    // 32MB [h*512+i][b,k]
  unsigned short* Sb  = (unsigned short*)(ws + 36 * MB);   // 64MB [b,h,q,k]
  unsigned short* Wub = (unsigned short*)(ws + 100 * MB);  // 4MB  [512,4096]
  unsigned short* Wqt = (unsigned short*)(ws + 104 * MB);  // 4MB [h][i][k]
  unsigned short* Wkt = (unsigned short*)(ws + 108 * MB);  // 4MB
  unsigned short* Wvt = (unsigned short*)(ws + 112 * MB);  // 4MB
  unsigned short* Nh  = (unsigned short*)(ws + 116 * MB);  // 4MB [h][512][512]
  unsigned short* Gh  = (unsigned short*)(ws + 120 * MB);  // 4MB
  unsigned short* xM  = (unsigned short*)(ws + 124 * MB);  // 32MB [b,t,h,j]
  // Pk: 8 x [4096,512] fp32 = 64MB at [100,164): overlays Wub/W*t/Nh/Gh/xM --
  // all dead by PxG time (xb/xGt/Sb untouched).
  float* Pk = (float*)(ws + 100 * MB);

  cast2_kernel<<<2 * 2048, 256, 0, stream>>>(x, Wu, xb, Wub);

  // per-head transpose+cast of fp32 Wq, Wk, Wv
  wtrans_kernel<<<dim3(8, 8, 24), 256, 0, stream>>>(Wq, Wk, Wv, Wqt, Wkt, Wvt);

  // merged small GEMMs (64 blocks): hh<8: Nh_h = Wkt_h.Wqt_h^T;
  // hh>=8 (h2): Gh_h2 = Wu_h2 . Wvt_h2^T  (A=Wub col-slice, lda2=4096)
  gemm_bt2<unsigned short><<<dim3(2, 2, 16), 512, 0, stream>>>(
      Wkt, Wqt, Nh,
      512, 512, 512, 512, 4,
      0, 262144LL, 0, 262144LL, 0, 262144LL, 1.0f,
      Wub, Wvt, Gh, 4096, 512LL, 262144LL, 262144LL, 8);

  // merged xM + xGt (512 blocks): hh<8: xM_h = x.Nh_h^T (m0=by,n0=bx);
  // hh>=8 (h2): xGt_h2 = Gh_h2 . x^T (m0=bx,n0=by -- swapped roles)
  gemm_bt2<unsigned short><<<dim3(2, 16, 16), 512, 0, stream>>>(
      xb, Nh, xM,
      512, 512, 512, 4096, 4,
      0, 0, 0, 262144LL, 0, 512LL, 1.0f,
      Gh, xb, xGt, 512, 262144LL, 0, 2097152LL, 8);

  // S = a * xM_{b,h} . x_b^T   (M=N=1024, K=512, 32 batches)
  gemm_bt2<unsigned short><<<dim3(4, 4, 32), 512, 0, stream>>>(
      xM, xb, Sb,
      512, 4096, 512, 1024, 3,
      4194304LL, 512LL, 524288LL, 0, 8388608LL, 1048576LL,
      0.044194173824159216f,
      nullptr, nullptr, nullptr, 0, 0, 0, 0, -1);

  // P = softmax(S - mask) in place; one block per (b,q), 8 waves = 8 heads
  softmax_kernel<<<4096, 512, 0, stream>>>(Sb, mask);

  // PxG: partial[h][b*1024+q][i] = sum_k P[b,h,q,k] * xGt[h*512+i][b*1024+k]
  gemm_bt2<float><<<dim3(2, 4, 32), 512, 0, stream>>>(
      Sb, xGt, Pk,
      1024, 1024, 4096, 512, 3,
      8388608LL, 1048576LL, 1024LL, 2097152LL, 524288LL, 2097152LL, 1.0f,
      nullptr, nullptr, nullptr, 0, 0, 0, 0, -1);

  // out = sum_h Pk[h] + bu
  reduce_kernel<<<2048, 256, 0, stream>>>(Pk, bu, (float*)d_out);
}

// Round 21
// 209.300 us; speedup vs baseline: 1.3254x; 1.0393x over previous
//
#include <hip/hip_runtime.h>
#include <hip/hip_bf16.h>

// B=4, T=1024, E=512, H=8. Both-sides algebraic rewrite (R18+R19):
//   S_h = x.(Wq_h^T Wk_h).x^T ; out = sum_h P_h.(x.G_h^T)+bu, G_h=Wu_h.Wv_h.
// GEMM work: NhGh 4.3 + xM/xGt 34.4 + S 34.4 + PxG 34.4 = 107.5 GF (minimal).
// R21: PxG writes bf16 partials (64->32MB), reduce reads bf16 (saves ~10us).
// gemm_bt2 core (R12-proven, UNCHANGED): 256x256, BK=32, 512thr/8w, 3-buf
// counted-vmcnt, T5 setprio, T1 bijective XCD swizzle (all grids % 8 == 0).
// MEASURED LAWS (R5-R20): (512,1) no spill; rate pins at ~550-600 TF across
// every schedule/tile variant (m233 2-phase ceiling; deep-pipeline templates
// don't reproduce at K=512-1024 = 8-16 K-tiles) -> FLOPs+overhead only.
// Layouts: xM [b,t,h,j] ld 4096; xGt [h*512+i][b*1024+k] ld 4096;
//   S/P [b,h,q,k]; Wqt/Wkt/Wvt [h][i][k]; Nh/Gh [h][512][512];
//   Pk = 8 x [4096,512] bf16 partials (overlays dead weights/xM, audited).

typedef short bf16x8 __attribute__((ext_vector_type(8)));
typedef float f32x4 __attribute__((ext_vector_type(4)));
typedef unsigned short u16x8 __attribute__((ext_vector_type(8)));

__device__ __forceinline__ unsigned short f2bf(float f) {
  unsigned int u = __float_as_uint(f);
  u += 0x7FFFu + ((u >> 16) & 1u);            // RNE, finite inputs
  return (unsigned short)(u >> 16);
}
__device__ __forceinline__ float bf2f(unsigned short s) {
  return __uint_as_float(((unsigned int)s) << 16);
}

typedef const __attribute__((address_space(1))) unsigned int* gas1_t;
typedef __attribute__((address_space(3))) unsigned int* las3_t;

__device__ __forceinline__ void gload16(const unsigned short* g, unsigned short* l) {
  __builtin_amdgcn_global_load_lds((gas1_t)g, (las3_t)l, 16, 0, 0);
}

__device__ __forceinline__ void store_val(unsigned short* p, float v) { *p = f2bf(v); }
__device__ __forceinline__ void store_val(float* p, float v) { *p = v; }

// ---------------- 256x256-tile BT GEMM, BK=32, 3-buf counted-vmcnt ----------------
// Dual-config: selGE>=0 && hh>=selGE -> (A2,B2,C2,lda2), h2=hh-selGE, and
// m0/n0 roles SWAPPED (supports transposed-shape second config).
template<typename OutT>
__global__ __launch_bounds__(512, 1) void gemm_bt2(
    const unsigned short* __restrict__ A, const unsigned short* __restrict__ B,
    OutT* __restrict__ C,
    int K, int lda, int ldb, int ldc, int zshift,
    long long sAb, long long sAh, long long sBb, long long sBh,
    long long sCb, long long sCh, float alpha,
    const unsigned short* __restrict__ A2, const unsigned short* __restrict__ B2,
    OutT* __restrict__ C2, int lda2,
    long long sA2h, long long sB2h, long long sC2h, int selGE)
{
  const int tid  = threadIdx.x;
  const int lane = tid & 63;
  const int wave = tid >> 6;
  const int l15 = lane & 15, lhi = lane >> 4;
  const int wm = wave >> 2, wn = wave & 3;           // 2M x 4N wave grid

  const int nx = gridDim.x, nxy = gridDim.x * gridDim.y;
  const int nwg = nxy * gridDim.z;
  int flat = blockIdx.x + nx * blockIdx.y + nxy * blockIdx.z;
  flat = (flat & 7) * (nwg >> 3) + (flat >> 3);
  const int bz = flat / nxy;
  const int rem = flat - bz * nxy;
  const int by = rem / nx;
  const int bx = rem - by * nx;

  const int bb = bz >> zshift, hh = bz & ((1 << zshift) - 1);

  const unsigned short* Ab;
  const unsigned short* Bb;
  OutT* Cb;
  int ldaU = lda;
  long long m0, n0;
  if (selGE >= 0 && hh >= selGE) {
    const int h2 = hh - selGE;
    Ab = A2 + (size_t)h2 * sA2h;
    Bb = B2 + (size_t)h2 * sB2h;
    Cb = C2 + (size_t)h2 * sC2h;
    ldaU = lda2;
    m0 = (long long)bx * 256;                        // swapped roles
    n0 = (long long)by * 256;
  } else {
    Ab = A + bb * sAb + hh * sAh;
    Bb = B + bb * sBb + hh * sBh;
    Cb = C + bb * sCb + hh * sCh;
    m0 = (long long)by * 256;
    n0 = (long long)bx * 256;
  }

  __shared__ __align__(16) unsigned short lds[49152];  // 96 KB, 3 buffers

  const unsigned short* gA[2];
  const unsigned short* gB[2];
  int fidx[2];
#pragma unroll
  for (int c = 0; c < 2; ++c) {
    const int f = c * 8 + wave;
    fidx[c] = f;
    gA[c] = Ab + (size_t)(m0 + f * 16 + l15) * ldaU + lhi * 8;
    gB[c] = Bb + (size_t)(n0 + f * 16 + l15) * ldb + lhi * 8;
  }

  auto stage = [&](int n, int p) {
    unsigned short* dst = lds + p * 16384;
    const int ko = n * 32;
#pragma unroll
    for (int c = 0; c < 2; ++c) {
      gload16(gA[c] + ko, dst + fidx[c] * 512);
      gload16(gB[c] + ko, dst + 8192 + fidx[c] * 512);
    }
  };

  f32x4 acc[8][4];
#pragma unroll
  for (int m = 0; m < 8; ++m)
#pragma unroll
    for (int n = 0; n < 4; ++n) acc[m][n] = (f32x4){0.f, 0.f, 0.f, 0.f};

  const int nt = K >> 5;
  stage(0, 0);
  stage(1, 1);
  asm volatile("s_waitcnt vmcnt(4)" ::: "memory");
  __builtin_amdgcn_sched_barrier(0);
  __builtin_amdgcn_s_barrier();

  for (int t = 0; t < nt; ++t) {
    const bool pref = (t + 2 < nt);
    if (pref) stage(t + 2, (t + 2) % 3);
    const unsigned short* base = lds + (t % 3) * 16384;
    bf16x8 af[8], bf[4];
#pragma unroll
    for (int mf = 0; mf < 8; ++mf)
      af[mf] = *(const bf16x8*)(base + (wm * 8 + mf) * 512 + lane * 8);
#pragma unroll
    for (int nf = 0; nf < 4; ++nf)
      bf[nf] = *(const bf16x8*)(base + 8192 + (wn * 4 + nf) * 512 + lane * 8);
    __builtin_amdgcn_s_setprio(1);
#pragma unroll
    for (int mf = 0; mf < 8; ++mf)
#pragma unroll
      for (int nf = 0; nf < 4; ++nf)
        acc[mf][nf] = __builtin_amdgcn_mfma_f32_16x16x32_bf16(af[mf], bf[nf], acc[mf][nf], 0, 0, 0);
    __builtin_amdgcn_s_setprio(0);
    if (pref) asm volatile("s_waitcnt vmcnt(4)" ::: "memory");
    else      asm volatile("s_waitcnt vmcnt(0)" ::: "memory");
    __builtin_amdgcn_sched_barrier(0);
    __builtin_amdgcn_s_barrier();
    __builtin_amdgcn_sched_barrier(0);
  }

  // C/D layout (m89/m91): col = lane&15, row = (lane>>4)*4 + reg
#pragma unroll
  for (int mf = 0; mf < 8; ++mf) {
#pragma unroll
    for (int nf = 0; nf < 4; ++nf) {
      const long long col = n0 + wn * 64 + nf * 16 + l15;
#pragma unroll
      for (int r = 0; r < 4; ++r) {
        const long long row = m0 + wm * 128 + mf * 16 + lhi * 4 + r;
        store_val(Cb + (size_t)row * ldc + col, acc[mf][nf][r] * alpha);
      }
    }
  }
}

// ---------------- per-head transpose + cast: Wt[h][i][k] = bf16(W[h*512+k][i]) ----------------
__global__ __launch_bounds__(256) void wtrans_kernel(
    const float* __restrict__ Wq, const float* __restrict__ Wk,
    const float* __restrict__ Wv,
    unsigned short* __restrict__ Wqt, unsigned short* __restrict__ Wkt,
    unsigned short* __restrict__ Wvt)
{
  __shared__ unsigned short t[64][72];
  const int k0 = blockIdx.x * 64;
  const int i0 = blockIdx.y * 64;
  const int hz = blockIdx.z;
  const int h = hz & 7;
  const int w = hz >> 3;
  const float* src = (w == 0) ? Wq : ((w == 1) ? Wk : Wv);
  unsigned short* dst = (w == 0) ? Wqt : ((w == 1) ? Wkt : Wvt);
  const int tid = threadIdx.x;
  const int r = tid >> 2, c16 = (tid & 3) * 16;
  const float* sp = src + (size_t)(h * 512 + k0 + r) * 512 + i0 + c16;
#pragma unroll
  for (int g = 0; g < 4; ++g) {
    float4 v = *(const float4*)(sp + g * 4);
    t[r][c16 + g * 4 + 0] = f2bf(v.x);
    t[r][c16 + g * 4 + 1] = f2bf(v.y);
    t[r][c16 + g * 4 + 2] = f2bf(v.z);
    t[r][c16 + g * 4 + 3] = f2bf(v.w);
  }
  __syncthreads();
  unsigned short o[16];
#pragma unroll
  for (int j = 0; j < 16; ++j) o[j] = t[c16 + j][r];
  unsigned short* dp = dst + (size_t)h * 262144 + (size_t)(i0 + r) * 512 + k0 + c16;
  *(u16x8*)dp = *(u16x8*)o;
  *(u16x8*)(dp + 8) = *(u16x8*)(o + 8);
}

// ---------------- 8-way bf16-partial reduce: out = sum_h(partials) + bias ----------------
__global__ __launch_bounds__(256) void reduce_kernel(
    const unsigned short* __restrict__ P, const float* __restrict__ bias,
    float* __restrict__ out)
{
  const int i = blockIdx.x * 256 + threadIdx.x;      // 4 outputs per thread
  const int col4 = i & 127;
  float4 s = ((const float4*)bias)[col4];
#pragma unroll
  for (int z = 0; z < 8; ++z) {
    uint2 v = *(const uint2*)(P + (size_t)z * 2097152 + (size_t)i * 4);
    s.x += bf2f((unsigned short)(v.x & 0xffffu));
    s.y += bf2f((unsigned short)(v.x >> 16));
    s.z += bf2f((unsigned short)(v.y & 0xffffu));
    s.w += bf2f((unsigned short)(v.y >> 16));
  }
  ((float4*)out)[i] = s;
}

// ---------------- fp32 -> bf16 cast of x and Wu ----------------
__global__ __launch_bounds__(256) void cast2_kernel(
    const float* __restrict__ s0, const float* __restrict__ s1,
    unsigned short* __restrict__ d0, unsigned short* __restrict__ d1)
{
  const int seg = blockIdx.x >> 11;
  const int off = (blockIdx.x & 2047) * 256 + threadIdx.x;
  const float* s = seg ? s1 : s0;
  unsigned short* d = seg ? d1 : d0;
  float4 v = ((const float4*)s)[off];
  ushort4 o;
  o.x = f2bf(v.x); o.y = f2bf(v.y); o.z = f2bf(v.z); o.w = f2bf(v.w);
  ((ushort4*)d)[off] = o;
}

// ---------------- softmax: one block per (b,q); wave w = head w ----------------
__global__ __launch_bounds__(512) void softmax_kernel(
    unsigned short* __restrict__ S, const float* __restrict__ mask)
{
  const int wave = threadIdx.x >> 6;                 // head
  const int lane = threadIdx.x & 63;
  const int bq = blockIdx.x;                         // 0..4095
  const int b = bq >> 10, q = bq & 1023;
  unsigned short* Srow = S + (((size_t)(b * 8 + wave)) * 1024 + q) * 1024;
  const float* mrow = mask + ((size_t)(b * 1024 + q)) * 1024;

  u16x8 sv0 = ((const u16x8*)Srow)[lane * 2];
  u16x8 sv1 = ((const u16x8*)Srow)[lane * 2 + 1];
  float mk[16];
  const float4* m4 = (const float4*)mrow + lane * 4;
#pragma unroll
  for (int t = 0; t < 4; ++t) {
    float4 v = m4[t];
    mk[t * 4 + 0] = v.x; mk[t * 4 + 1] = v.y; mk[t * 4 + 2] = v.z; mk[t * 4 + 3] = v.w;
  }

  float lg[16];
#pragma unroll
  for (int j = 0; j < 8; ++j) lg[j] = bf2f(sv0[j]) - mk[j];
#pragma unroll
  for (int j = 0; j < 8; ++j) lg[8 + j] = bf2f(sv1[j]) - mk[8 + j];

  float mx = lg[0];
#pragma unroll
  for (int j = 1; j < 16; ++j) mx = fmaxf(mx, lg[j]);
#pragma unroll
  for (int off = 32; off > 0; off >>= 1) mx = fmaxf(mx, __shfl_xor(mx, off));

  float ex[16], sm = 0.f;
#pragma unroll
  for (int j = 0; j < 16; ++j) { ex[j] = __expf(lg[j] - mx); sm += ex[j]; }
#pragma unroll
  for (int off = 32; off > 0; off >>= 1) sm += __shfl_xor(sm, off);
  const float rinv = 1.0f / sm;

  u16x8 o0, o1;
#pragma unroll
  for (int j = 0; j < 8; ++j) o0[j] = f2bf(ex[j] * rinv);
#pragma unroll
  for (int j = 0; j < 8; ++j) o1[j] = f2bf(ex[8 + j] * rinv);
  ((u16x8*)Srow)[lane * 2] = o0;
  ((u16x8*)Srow)[lane * 2 + 1] = o1;
}

extern "C" void kernel_launch(void* const* d_in, const int* in_sizes, int n_in,
                              void* d_out, int out_size, void* d_ws, size_t ws_size,
                              hipStream_t stream) {
  const float* x    = (const float*)d_in[0];
  const float* mask = (const float*)d_in[1];
  const float* Wk   = (const float*)d_in[2];
  const float* Wq   = (const float*)d_in[3];
  const float* Wv   = (const float*)d_in[4];
  const float* Wu   = (const float*)d_in[5];
  const float* bu   = (const float*)d_in[6];

  const size_t MB = 1024 * 1024;
  if (ws_size < 192 * MB) return;
  char* ws = (char*)d_ws;
  unsigned short* xb  = (unsigned short*)(ws + 0 * MB);    // 4MB  [4096,512]
  unsigned short* xGt = (unsigned short*)(ws + 4 * MB);    // 32MB [h*512+i][b,k]
  unsigned short* Sb  = (unsigned short*)(ws + 36 * MB);   // 64MB [b,h,q,k]
  unsigned short* Wub = (unsigned short*)(ws + 100 * MB);  // 4MB  [512,4096]
  unsigned short* Wqt = (unsigned short*)(ws + 104 * MB);  // 4MB [h][i][k]
  unsigned short* Wkt = (unsigned short*)(ws + 108 * MB);  // 4MB
  unsigned short* Wvt = (unsigned short*)(ws + 112 * MB);  // 4MB
  unsigned short* Nh  = (unsigned short*)(ws + 116 * MB);  // 4MB [h][512][512]
  unsigned short* Gh  = (unsigned short*)(ws + 120 * MB);  // 4MB
  unsigned short* xM  = (unsigned short*)(ws + 124 * MB);  // 32MB [b,t,h,j]
  // Pk: 8 x [4096,512] bf16 = 32MB at [100,132): overlays Wub/W*t/Nh/Gh + xM
  // head -- all dead by PxG time (xb/xGt/Sb untouched).
  unsigned short* Pk = (unsigned short*)(ws + 100 * MB);

  cast2_kernel<<<2 * 2048, 256, 0, stream>>>(x, Wu, xb, Wub);

  // per-head transpose+cast of fp32 Wq, Wk, Wv
  wtrans_kernel<<<dim3(8, 8, 24), 256, 0, stream>>>(Wq, Wk, Wv, Wqt, Wkt, Wvt);

  // merged small GEMMs (64 blocks): hh<8: Nh_h = Wkt_h.Wqt_h^T;
  // hh>=8 (h2): Gh_h2 = Wu_h2 . Wvt_h2^T  (A=Wub col-slice, lda2=4096)
  gemm_bt2<unsigned short><<<dim3(2, 2, 16), 512, 0, stream>>>(
      Wkt, Wqt, Nh,
      512, 512, 512, 512, 4,
      0, 262144LL, 0, 262144LL, 0, 262144LL, 1.0f,
      Wub, Wvt, Gh, 4096, 512LL, 262144LL, 262144LL, 8);

  // merged xM + xGt (512 blocks): hh<8: xM_h = x.Nh_h^T (m0=by,n0=bx);
  // hh>=8 (h2): xGt_h2 = Gh_h2 . x^T (m0=bx,n0=by -- swapped roles)
  gemm_bt2<unsigned short><<<dim3(2, 16, 16), 512, 0, stream>>>(
      xb, Nh, xM,
      512, 512, 512, 4096, 4,
      0, 0, 0, 262144LL, 0, 512LL, 1.0f,
      Gh, xb, xGt, 512, 262144LL, 0, 2097152LL, 8);

  // S = a * xM_{b,h} . x_b^T   (M=N=1024, K=512, 32 batches)
  gemm_bt2<unsigned short><<<dim3(4, 4, 32), 512, 0, stream>>>(
      xM, xb, Sb,
      512, 4096, 512, 1024, 3,
      4194304LL, 512LL, 524288LL, 0, 8388608LL, 1048576LL,
      0.044194173824159216f,
      nullptr, nullptr, nullptr, 0, 0, 0, 0, -1);

  // P = softmax(S - mask) in place; one block per (b,q), 8 waves = 8 heads
  softmax_kernel<<<4096, 512, 0, stream>>>(Sb, mask);

  // PxG (bf16 partials): Pk[h][b*1024+q][i] = sum_k P[b,h,q,k]*xGt[h*512+i][b*1024+k]
  gemm_bt2<unsigned short><<<dim3(2, 4, 32), 512, 0, stream>>>(
      Sb, xGt, Pk,
      1024, 1024, 4096, 512, 3,
      8388608LL, 1048576LL, 1024LL, 2097152LL, 524288LL, 2097152LL, 1.0f,
      nullptr, nullptr, nullptr, 0, 0, 0, 0, -1);

  // out = sum_h Pk[h] + bu
  reduce_kernel<<<2048, 256, 0, stream>>>(Pk, bu, (float*)d_out);
}